// Round 10
// baseline (350.662 us; speedup 1.0000x reference)
//
#include <hip/hip_runtime.h>
#include <hip/hip_bf16.h>
#include <hip/hip_fp16.h>
#include <stdint.h>

typedef _Float16 half_t;
typedef _Float16 half8 __attribute__((ext_vector_type(8)));
typedef float f32x4 __attribute__((ext_vector_type(4)));

#define NN 4096
// ws layout (bytes). S1/X1: fp16 [64][512][64] hybrid (k-block, j=b*64+d, k-in-block)
// x1 aliases s1 (dead after layer-1 gemm); y aliases xp (dead after k2e).
#define OFF_W1THI  0u
#define OFF_W1TLO  16384u
#define OFF_S1HI   32768u
#define OFF_S1LO   (32768u + 4194304u)
#define OFF_XP0    (32768u + 2u*4194304u)
#define OFF_XP1    (OFF_XP0 + 8388608u)
// total 25,198,592 bytes (proven footprint)

__device__ __forceinline__ float sigmoidf_(float x) { return 1.f / (1.f + __expf(-x)); }
__device__ __forceinline__ float tanhf_(float x)    { return 1.f - 2.f / (__expf(2.f * x) + 1.f); }

// ---- K0: transpose + hi/lo split W1 [96][64] -> W1t [64][96] fp16 pairs
__global__ void prep_w1t(const float* __restrict__ w1,
                         half_t* __restrict__ whi, half_t* __restrict__ wlo) {
    int i = blockIdx.x * 256 + threadIdx.x;
    if (i >= 96 * 64) return;
    int c = i >> 6, d = i & 63;
    float v = w1[i];
    half_t h = (half_t)v;
    whi[d * 96 + c] = h;
    wlo[d * 96 + c] = (half_t)(v - (float)h);
}

// ---- K1: S1[kb][j][kc] (j=b*64+d) = sum_c combined[b][n][c]*W1[c][d], 3-pass fp16
__global__ __launch_bounds__(256) void k1_gemm(
    const float* __restrict__ inp, const float* __restrict__ hcur,
    const half_t* __restrict__ wthi, const half_t* __restrict__ wtlo,
    half_t* __restrict__ s1hi, half_t* __restrict__ s1lo)
{
    __shared__ half_t Ch[64 * 96], Cl[64 * 96], Wh[64 * 96], Wl[64 * 96];
    const int t = threadIdx.x;
    const int l = t & 63, w = t >> 6, lr = l & 15, lg = l >> 4;
    const int b = blockIdx.x >> 6;
    const int kb = blockIdx.x & 63;
    const int nBase = kb * 64;

    {
        const uint32_t* sh = (const uint32_t*)wthi;
        const uint32_t* sl = (const uint32_t*)wtlo;
        uint32_t* dh = (uint32_t*)Wh;
        uint32_t* dl = (uint32_t*)Wl;
        for (int i = t; i < 3072; i += 256) { dh[i] = sh[i]; dl[i] = sl[i]; }
    }
#pragma unroll
    for (int i = 0; i < 6; ++i) {
        int f4 = t + i * 256;
        int row = f4 / 24, slot = f4 % 24;
        int n = nBase + row;
        f32x4 v; int c0;
        if (slot < 8) { c0 = slot * 4; v = *(const f32x4*)(inp + ((size_t)b * NN + n) * 32 + c0); }
        else { c0 = 32 + (slot - 8) * 4; v = *(const f32x4*)(hcur + ((size_t)b * NN + n) * 64 + (c0 - 32)); }
#pragma unroll
        for (int jj = 0; jj < 4; ++jj) {
            float x = v[jj];
            half_t hh = (half_t)x;
            Ch[row * 96 + c0 + jj] = hh;
            Cl[row * 96 + c0 + jj] = (half_t)(x - (float)hh);
        }
    }
    __syncthreads();

    const f32x4 z = {0.f, 0.f, 0.f, 0.f};
    f32x4 acc[4] = {z, z, z, z};
#pragma unroll
    for (int kk = 0; kk < 3; ++kk) {
        const int qo = (w * 16 + lr) * 96 + kk * 32 + lg * 8;
        half8 cf_h = *(const half8*)(Ch + qo);
        half8 cf_l = *(const half8*)(Cl + qo);
#pragma unroll
        for (int dt = 0; dt < 4; ++dt) {
            const int po = (dt * 16 + lr) * 96 + kk * 32 + lg * 8;
            half8 wf_h = *(const half8*)(Wh + po);
            half8 wf_l = *(const half8*)(Wl + po);
            acc[dt] = __builtin_amdgcn_mfma_f32_16x16x32_f16(wf_h, cf_h, acc[dt], 0, 0, 0);
            acc[dt] = __builtin_amdgcn_mfma_f32_16x16x32_f16(wf_h, cf_l, acc[dt], 0, 0, 0);
            acc[dt] = __builtin_amdgcn_mfma_f32_16x16x32_f16(wf_l, cf_h, acc[dt], 0, 0, 0);
        }
    }
    const int kc = w * 16 + lr;
#pragma unroll
    for (int dt = 0; dt < 4; ++dt)
#pragma unroll
        for (int j4 = 0; j4 < 4; ++j4) {
            int d = dt * 16 + lg * 4 + j4;
            float v = acc[dt][j4];
            half_t hh = (half_t)v;
            size_t o = ((size_t)kb * 512 + b * 64 + d) * 64 + kc;
            s1hi[o] = hh;
            s1lo[o] = (half_t)(v - (float)hh);
        }
}

// ---- K2/K3 unified: C[m][j] = sum_n (adj*mask)[m,n] * X[n][j]
// M=4096, N(j)=512, K=4096; BM=BN=128, BK=64, ks x2 partials.
// 1024 threads = 16 waves (4m x 4n), wave tile 32x32.
// A (adj*mask fp16 hi/lo): double-buffered LDS (64 KB) + reg prefetch.
// X: NO LDS — hybrid [kb][j][kc] layout makes each MFMA B-fragment a
// contiguous 16B global load (compile-time offsets); X is L2-resident (8 MB),
// loaded straight into registers each step. Halves LDS traffic (the measured
// bottleneck rounds 5-9) and moves X to the parallel L2 port.
__global__ __launch_bounds__(1024) void gemm_bn(
    const float* __restrict__ adj, const float* __restrict__ mask,
    const half_t* __restrict__ xhi, const half_t* __restrict__ xlo,
    float* __restrict__ out0, float* __restrict__ out1)
{
    __shared__ half_t Ah[2 * 128 * 64], Al[2 * 128 * 64];   // 64 KB total
    const int t = threadIdx.x;
    const int l = t & 63, w = t >> 6, lr = l & 15, lg = l >> 4;
    const int wm = w >> 2, wn = w & 3;
    const int bx = blockIdx.x;
    const int mt_ = bx & 31, ks = (bx >> 5) & 1, nb = bx >> 6;
    const int mBase = mt_ * 128, jBase = nb * 128;
    float* __restrict__ outp = ks ? out1 : out0;

    const f32x4 z = {0.f, 0.f, 0.f, 0.f};
    f32x4 acc[2][2] = {{z, z}, {z, z}};

    const int srow = t >> 3, skc = t & 7;   // staging slot: 128 rows x 8 chunks
    const int sbyte = (srow * 128 + skc * 16) ^ ((srow & 7) << 4);

    // A prefetch registers (tile it+1)
    f32x4 pa0, pa1, pm0, pm1;

    // per-lane X base (halfs): col = jBase + wn*32 + lr, k-sub = lg*8
    size_t xbase = ((size_t)(ks * 32) * 512 + jBase + wn * 32 + lr) * 64 + lg * 8;

#define ISSUE_A(IT)                                                              \
    {                                                                            \
        const int kb = ks * 32 + (IT);                                           \
        size_t ga = (size_t)(mBase + srow) * NN + kb * 64 + skc * 8;             \
        pa0 = *(const f32x4*)(adj + ga);                                         \
        pa1 = *(const f32x4*)(adj + ga + 4);                                     \
        pm0 = *(const f32x4*)(mask + ga);                                        \
        pm1 = *(const f32x4*)(mask + ga + 4);                                    \
    }

#define CONVERT_WRITE_A(P)                                                       \
    {                                                                            \
        const int off = (P) * 16384;                                             \
        half8 hv, lv;                                                            \
        _Pragma("unroll")                                                        \
        for (int jj = 0; jj < 4; ++jj) {                                         \
            float p0 = pa0[jj] * pm0[jj];                                        \
            float p1 = pa1[jj] * pm1[jj];                                        \
            half_t h0 = (half_t)p0, h1 = (half_t)p1;                             \
            hv[jj] = h0; hv[jj + 4] = h1;                                        \
            lv[jj] = (half_t)(p0 - (float)h0);                                   \
            lv[jj + 4] = (half_t)(p1 - (float)h1);                               \
        }                                                                        \
        *(half8*)((char*)Ah + off + sbyte) = hv;                                 \
        *(half8*)((char*)Al + off + sbyte) = lv;                                 \
    }

    ISSUE_A(0);
    CONVERT_WRITE_A(0);
    __syncthreads();

    for (int it = 0; it < 32; ++it) {
        const int p = it & 1;
        const int pofs = p * 16384;
        if (it + 1 < 32) ISSUE_A(it + 1);          // A global loads in flight
        __builtin_amdgcn_sched_barrier(0);
        // X fragments for THIS step, straight from global/L2 (16B each,
        // compile-time offsets off one per-lane base). [kk][nt]
        half8 fxh[2][2], fxl[2][2];
#pragma unroll
        for (int kk = 0; kk < 2; ++kk)
#pragma unroll
            for (int nt = 0; nt < 2; ++nt) {
                size_t gx = xbase + (size_t)nt * 1024 + kk * 32;
                fxh[kk][nt] = *(const half8*)(xhi + gx);
                fxl[kk][nt] = *(const half8*)(xlo + gx);
            }
        xbase += 512 * 64;                          // next kb
        __builtin_amdgcn_sched_barrier(0);
#pragma unroll
        for (int kk = 0; kk < 2; ++kk) {
            half8 fa_h[2], fa_l[2];
#pragma unroll
            for (int mt = 0; mt < 2; ++mt) {
                int r = wm * 32 + mt * 16 + lr;
                int byte = ((r * 128 + kk * 64 + lg * 16) ^ ((r & 7) << 4)) + pofs;
                fa_h[mt] = *(const half8*)((const char*)Ah + byte);
                fa_l[mt] = *(const half8*)((const char*)Al + byte);
            }
            __builtin_amdgcn_sched_barrier(0);      // batch reads, one drain
#pragma unroll
            for (int mt = 0; mt < 2; ++mt)
#pragma unroll
                for (int nt = 0; nt < 2; ++nt) {
                    acc[mt][nt] = __builtin_amdgcn_mfma_f32_16x16x32_f16(fa_h[mt], fxh[kk][nt], acc[mt][nt], 0, 0, 0);
                    acc[mt][nt] = __builtin_amdgcn_mfma_f32_16x16x32_f16(fa_l[mt], fxh[kk][nt], acc[mt][nt], 0, 0, 0);
                    acc[mt][nt] = __builtin_amdgcn_mfma_f32_16x16x32_f16(fa_h[mt], fxl[kk][nt], acc[mt][nt], 0, 0, 0);
                }
        }
        if (it + 1 < 32) CONVERT_WRITE_A(p ^ 1);   // write NEXT buffer
        __syncthreads();                           // one barrier per k-step
    }

    // C store: row m' = mBase+wm*32+mt*16+lg*4+j4, col j' = jBase+wn*32+nt*16+lr
#pragma unroll
    for (int mt = 0; mt < 2; ++mt)
#pragma unroll
        for (int nt = 0; nt < 2; ++nt) {
            int jcol = jBase + wn * 32 + nt * 16 + lr;
#pragma unroll
            for (int j4 = 0; j4 < 4; ++j4) {
                int mrow = mBase + wm * 32 + mt * 16 + lg * 4 + j4;
                outp[(size_t)mrow * 512 + jcol] = acc[mt][nt][j4];
            }
        }
#undef ISSUE_A
#undef CONVERT_WRITE_A
}

// ---- K2e: x1[kb][j][kc] = relu(xp0+xp1+b1[j&63]) split hi/lo
__global__ __launch_bounds__(256) void k2e(
    const float* __restrict__ p0, const float* __restrict__ p1,
    const float* __restrict__ b1,
    half_t* __restrict__ xhi, half_t* __restrict__ xlo)
{
    int base = blockIdx.x * 256 + threadIdx.x;
#pragma unroll
    for (int rpt = 0; rpt < 4; ++rpt) {
        int idx4 = base + rpt * 131072;
        int m = idx4 >> 7, jq = idx4 & 127;
        int j0 = jq * 4, d0 = j0 & 63;
        size_t e = (size_t)m * 512 + j0;
        f32x4 v = *(const f32x4*)(p0 + e);
        f32x4 u = *(const f32x4*)(p1 + e);
        f32x4 bb = *(const f32x4*)(b1 + d0);
        size_t obase = ((size_t)(m >> 6) * 512 + j0) * 64 + (m & 63);
#pragma unroll
        for (int jj = 0; jj < 4; ++jj) {
            float x = v[jj] + u[jj] + bb[jj];
            x = fmaxf(x, 0.f);
            half_t hh = (half_t)x;
            xhi[obase + (size_t)jj * 64] = hh;
            xlo[obase + (size_t)jj * 64] = (half_t)(x - (float)hh);
        }
    }
}

// ---- K4: cc = Y@W2 + b2 (fp32, full W2 in LDS, static acc indices) + LSTM pointwise.
__global__ __launch_bounds__(256) void k4_final(
    const float* __restrict__ y0, const float* __restrict__ y1,
    const float* __restrict__ w2, const float* __restrict__ b2,
    const float* __restrict__ ccur,
    float* __restrict__ outh, float* __restrict__ outc)
{
    __shared__ float Yt[64 * 64];
    __shared__ float W2s[64 * 256];
    const int t = threadIdx.x;
    const int cb = t & 15, rb = t >> 4;
    const int rowBase = blockIdx.x * 64;
    const int bIdx = rowBase >> 12, mBase = rowBase & 4095;

#pragma unroll
    for (int i = 0; i < 4; ++i) {
        int id4 = t + i * 256;
        int r = id4 >> 4, dc = id4 & 15;
        size_t g = (size_t)(mBase + r) * 512 + bIdx * 64 + dc * 4;
        f32x4 v = *(const f32x4*)(y0 + g);
        f32x4 u = *(const f32x4*)(y1 + g);
#pragma unroll
        for (int jj = 0; jj < 4; ++jj) Yt[(dc * 4 + jj) * 64 + r] = v[jj] + u[jj];
    }
#pragma unroll
    for (int i = 0; i < 16; ++i) {
        int id4 = t + i * 256;
        *(f32x4*)(W2s + id4 * 4) = *(const f32x4*)(w2 + id4 * 4);
    }
    __syncthreads();

    const f32x4 z = {0.f, 0.f, 0.f, 0.f};
    f32x4 accG[4][4];
#pragma unroll
    for (int g = 0; g < 4; ++g)
#pragma unroll
        for (int r8 = 0; r8 < 4; ++r8) accG[g][r8] = z;

    for (int d = 0; d < 64; ++d) {
        f32x4 y4 = *(const f32x4*)(Yt + d * 64 + rb * 4);
#pragma unroll
        for (int g = 0; g < 4; ++g) {
            f32x4 w4 = *(const f32x4*)(W2s + d * 256 + g * 64 + cb * 4);
#pragma unroll
            for (int r8 = 0; r8 < 4; ++r8) accG[g][r8] += w4 * y4[r8];
        }
    }

    float b2i[4], b2f[4], b2o[4], b2g[4];
#pragma unroll
    for (int jj = 0; jj < 4; ++jj) {
        b2i[jj] = b2[0 * 64 + cb * 4 + jj];
        b2f[jj] = b2[1 * 64 + cb * 4 + jj];
        b2o[jj] = b2[2 * 64 + cb * 4 + jj];
        b2g[jj] = b2[3 * 64 + cb * 4 + jj];
    }
#pragma unroll
    for (int r8 = 0; r8 < 4; ++r8) {
        int row = rowBase + rb * 4 + r8;
        f32x4 c4 = *(const f32x4*)(ccur + (size_t)row * 64 + cb * 4);
        f32x4 hv, cv;
#pragma unroll
        for (int jj = 0; jj < 4; ++jj) {
            float ii = sigmoidf_(accG[0][r8][jj] + b2i[jj]);
            float ff = sigmoidf_(accG[1][r8][jj] + b2f[jj]);
            float oo = sigmoidf_(accG[2][r8][jj] + b2o[jj]);
            float gg = tanhf_(accG[3][r8][jj] + b2g[jj]);
            float cn = ff * c4[jj] + ii * gg;
            float hn = oo * tanhf_(cn);
            hv[jj] = hn;
            cv[jj] = cn;
        }
        *(f32x4*)(outh + (size_t)row * 64 + cb * 4) = hv;
        *(f32x4*)(outc + (size_t)row * 64 + cb * 4) = cv;
    }
}

extern "C" void kernel_launch(void* const* d_in, const int* in_sizes, int n_in,
                              void* d_out, int out_size, void* d_ws, size_t ws_size,
                              hipStream_t stream) {
    const float* inp   = (const float*)d_in[0];
    const float* hcur  = (const float*)d_in[1];
    const float* ccur  = (const float*)d_in[2];
    const float* adj   = (const float*)d_in[3];
    const float* w1    = (const float*)d_in[4];
    const float* mask1 = (const float*)d_in[5];
    const float* b1    = (const float*)d_in[6];
    const float* w2    = (const float*)d_in[7];
    const float* mask2 = (const float*)d_in[8];
    const float* b2    = (const float*)d_in[9];

    char* ws = (char*)d_ws;
    half_t* w1thi = (half_t*)(ws + OFF_W1THI);
    half_t* w1tlo = (half_t*)(ws + OFF_W1TLO);
    half_t* s1hi  = (half_t*)(ws + OFF_S1HI);
    half_t* s1lo  = (half_t*)(ws + OFF_S1LO);
    half_t* x1hi  = (half_t*)(ws + OFF_S1HI);   // alias: s1 dead after layer-1 gemm
    half_t* x1lo  = (half_t*)(ws + OFF_S1LO);
    float*  xp0   = (float*)(ws + OFF_XP0);
    float*  xp1   = (float*)(ws + OFF_XP1);
    float*  y0    = (float*)(ws + OFF_XP0);     // alias: xp dead after k2e
    float*  y1    = (float*)(ws + OFF_XP1);

    float* hout = (float*)d_out;
    float* cout = hout + (size_t)8 * 4096 * 64;

    prep_w1t<<<24, 256, 0, stream>>>(w1, w1thi, w1tlo);
    k1_gemm<<<512, 256, 0, stream>>>(inp, hcur, w1thi, w1tlo, s1hi, s1lo);
    gemm_bn<<<256, 1024, 0, stream>>>(adj, mask1, s1hi, s1lo, xp0, xp1);
    k2e<<<512, 256, 0, stream>>>(xp0, xp1, b1, x1hi, x1lo);
    gemm_bn<<<256, 1024, 0, stream>>>(adj, mask2, x1hi, x1lo, y0, y1);
    k4_final<<<512, 256, 0, stream>>>(y0, y1, w2, b2, ccur, hout, cout);
}

// Round 12
// 338.779 us; speedup vs baseline: 1.0351x; 1.0351x over previous
//
#include <hip/hip_runtime.h>
#include <hip/hip_bf16.h>
#include <hip/hip_fp16.h>
#include <stdint.h>

typedef _Float16 half_t;
typedef _Float16 half8 __attribute__((ext_vector_type(8)));
typedef float f32x4 __attribute__((ext_vector_type(4)));

#define NN 4096
// ws layout (bytes). S1/X1: fp16 [64][512][64] hybrid (k-block, j=b*64+d, k-in-block)
#define OFF_W1THI  0u
#define OFF_W1TLO  16384u
#define OFF_S1HI   32768u
#define OFF_S1LO   (32768u + 4194304u)
#define OFF_XP0    (32768u + 2u*4194304u)
#define OFF_XP1    (OFF_XP0 + 8388608u)
// total 25,198,592 bytes (proven footprint)

__device__ __forceinline__ float sigmoidf_(float x) { return 1.f / (1.f + __expf(-x)); }
__device__ __forceinline__ float tanhf_(float x)    { return 1.f - 2.f / (__expf(2.f * x) + 1.f); }

// ---- K0: transpose + hi/lo split W1 [96][64] -> W1t [64][96] fp16 pairs
__global__ void prep_w1t(const float* __restrict__ w1,
                         half_t* __restrict__ whi, half_t* __restrict__ wlo) {
    int i = blockIdx.x * 256 + threadIdx.x;
    if (i >= 96 * 64) return;
    int c = i >> 6, d = i & 63;
    float v = w1[i];
    half_t h = (half_t)v;
    whi[d * 96 + c] = h;
    wlo[d * 96 + c] = (half_t)(v - (float)h);
}

// ---- K1: S1[kb][j][kc] (j=b*64+d) = sum_c combined[b][n][c]*W1[c][d], 3-pass fp16
__global__ __launch_bounds__(256) void k1_gemm(
    const float* __restrict__ inp, const float* __restrict__ hcur,
    const half_t* __restrict__ wthi, const half_t* __restrict__ wtlo,
    half_t* __restrict__ s1hi, half_t* __restrict__ s1lo)
{
    __shared__ half_t Ch[64 * 96], Cl[64 * 96], Wh[64 * 96], Wl[64 * 96];
    const int t = threadIdx.x;
    const int l = t & 63, w = t >> 6, lr = l & 15, lg = l >> 4;
    const int b = blockIdx.x >> 6;
    const int kb = blockIdx.x & 63;
    const int nBase = kb * 64;

    {
        const uint32_t* sh = (const uint32_t*)wthi;
        const uint32_t* sl = (const uint32_t*)wtlo;
        uint32_t* dh = (uint32_t*)Wh;
        uint32_t* dl = (uint32_t*)Wl;
        for (int i = t; i < 3072; i += 256) { dh[i] = sh[i]; dl[i] = sl[i]; }
    }
#pragma unroll
    for (int i = 0; i < 6; ++i) {
        int f4 = t + i * 256;
        int row = f4 / 24, slot = f4 % 24;
        int n = nBase + row;
        f32x4 v; int c0;
        if (slot < 8) { c0 = slot * 4; v = *(const f32x4*)(inp + ((size_t)b * NN + n) * 32 + c0); }
        else { c0 = 32 + (slot - 8) * 4; v = *(const f32x4*)(hcur + ((size_t)b * NN + n) * 64 + (c0 - 32)); }
#pragma unroll
        for (int jj = 0; jj < 4; ++jj) {
            float x = v[jj];
            half_t hh = (half_t)x;
            Ch[row * 96 + c0 + jj] = hh;
            Cl[row * 96 + c0 + jj] = (half_t)(x - (float)hh);
        }
    }
    __syncthreads();

    const f32x4 z = {0.f, 0.f, 0.f, 0.f};
    f32x4 acc[4] = {z, z, z, z};
#pragma unroll
    for (int kk = 0; kk < 3; ++kk) {
        const int qo = (w * 16 + lr) * 96 + kk * 32 + lg * 8;
        half8 cf_h = *(const half8*)(Ch + qo);
        half8 cf_l = *(const half8*)(Cl + qo);
#pragma unroll
        for (int dt = 0; dt < 4; ++dt) {
            const int po = (dt * 16 + lr) * 96 + kk * 32 + lg * 8;
            half8 wf_h = *(const half8*)(Wh + po);
            half8 wf_l = *(const half8*)(Wl + po);
            acc[dt] = __builtin_amdgcn_mfma_f32_16x16x32_f16(wf_h, cf_h, acc[dt], 0, 0, 0);
            acc[dt] = __builtin_amdgcn_mfma_f32_16x16x32_f16(wf_h, cf_l, acc[dt], 0, 0, 0);
            acc[dt] = __builtin_amdgcn_mfma_f32_16x16x32_f16(wf_l, cf_h, acc[dt], 0, 0, 0);
        }
    }
    const int kc = w * 16 + lr;
#pragma unroll
    for (int dt = 0; dt < 4; ++dt)
#pragma unroll
        for (int j4 = 0; j4 < 4; ++j4) {
            int d = dt * 16 + lg * 4 + j4;
            float v = acc[dt][j4];
            half_t hh = (half_t)v;
            size_t o = ((size_t)kb * 512 + b * 64 + d) * 64 + kc;
            s1hi[o] = hh;
            s1lo[o] = (half_t)(v - (float)hh);
        }
}

// ---- K2/K3 unified: C[m][j] = sum_n (adj*mask)[m,n] * X[n][j]
// Counted-vmcnt asm pipeline. Fixes vs round 11:
//  (1) final s_waitcnt vmcnt(0) after the loop — dangling async loads were
//      clobbering epilogue registers (the crash);
//  (2) "=&v" early-clobber on every async load output;
//  (3) A-pipeline off-by-one: STEP(IT) converts A(IT+1), issues A(IT+2);
//  (4) "memory" clobbers on waitcnt asm (orders ds_writes vs publish).
// Steady state at vmcnt(8): in-flight = X(cur)8 + A(next)4 + X(next)8 = 20
// -> drains exactly X(cur)+A(next), leaves X(next). Barrier is lgkmcnt-only
// so 12 loads stay in flight across it.
__global__ __launch_bounds__(1024) void gemm_bn(
    const float* __restrict__ adj, const float* __restrict__ mask,
    const half_t* __restrict__ xhi, const half_t* __restrict__ xlo,
    float* __restrict__ out0, float* __restrict__ out1)
{
    __shared__ half_t Ah[2 * 128 * 64], Al[2 * 128 * 64];   // 64 KB
    const int t = threadIdx.x;
    const int l = t & 63, w = t >> 6, lr = l & 15, lg = l >> 4;
    const int wm = w >> 2, wn = w & 3;
    const int bx = blockIdx.x;
    const int mt_ = bx & 31, ks = (bx >> 5) & 1, nb = bx >> 6;
    const int mBase = mt_ * 128, jBase = nb * 128;
    float* __restrict__ outp = ks ? out1 : out0;

    const f32x4 z = {0.f, 0.f, 0.f, 0.f};
    f32x4 acc[2][2] = {{z, z}, {z, z}};

    const int srow = t >> 3, skc = t & 7;   // staging slot: 128 rows x 8 chunks
    const int sbyte = (srow * 128 + skc * 16) ^ ((srow & 7) << 4);

    f32x4 pa0, pa1, pm0, pm1;                       // A stage regs
    half8 XAh[2][2], XAl[2][2], XBh[2][2], XBl[2][2];   // X frag regs [kk][nt]

    const size_t xb0 = (size_t)(jBase + wn * 32 + lr) * 64 + lg * 8;

#define ISSUE_A(KBN)                                                            \
    {                                                                           \
        size_t ga_ = (size_t)(mBase + srow) * NN                                \
                   + (size_t)(ks * 32 + (KBN)) * 64 + skc * 8;                  \
        const float* ap_ = adj + ga_;                                           \
        const float* mp_ = mask + ga_;                                          \
        asm volatile("global_load_dwordx4 %0, %2, off\n\t"                      \
                     "global_load_dwordx4 %1, %2, off offset:16"                \
                     : "=&v"(pa0), "=&v"(pa1) : "v"(ap_));                      \
        asm volatile("global_load_dwordx4 %0, %2, off\n\t"                      \
                     "global_load_dwordx4 %1, %2, off offset:16"                \
                     : "=&v"(pm0), "=&v"(pm1) : "v"(mp_));                      \
    }

#define ISSUE_X(H, L, KBN)                                                      \
    {                                                                           \
        const half_t* xph_ = xhi + xb0 + (size_t)(ks * 32 + (KBN)) * 32768;     \
        const half_t* xpl_ = xlo + xb0 + (size_t)(ks * 32 + (KBN)) * 32768;     \
        asm volatile("global_load_dwordx4 %0, %4, off\n\t"                      \
                     "global_load_dwordx4 %1, %4, off offset:64\n\t"            \
                     "global_load_dwordx4 %2, %4, off offset:2048\n\t"          \
                     "global_load_dwordx4 %3, %4, off offset:2112"              \
                     : "=&v"(H[0][0]), "=&v"(H[1][0]), "=&v"(H[0][1]),          \
                       "=&v"(H[1][1]) : "v"(xph_));                             \
        asm volatile("global_load_dwordx4 %0, %4, off\n\t"                      \
                     "global_load_dwordx4 %1, %4, off offset:64\n\t"            \
                     "global_load_dwordx4 %2, %4, off offset:2048\n\t"          \
                     "global_load_dwordx4 %3, %4, off offset:2112"              \
                     : "=&v"(L[0][0]), "=&v"(L[1][0]), "=&v"(L[0][1]),          \
                       "=&v"(L[1][1]) : "v"(xpl_));                             \
    }

#define CONVERT_WRITE_A(P)                                                      \
    {                                                                           \
        const int off = (P) * 16384;                                            \
        half8 hv, lv;                                                           \
        _Pragma("unroll")                                                       \
        for (int jj = 0; jj < 4; ++jj) {                                        \
            float p0 = pa0[jj] * pm0[jj];                                       \
            float p1 = pa1[jj] * pm1[jj];                                       \
            half_t h0 = (half_t)p0, h1 = (half_t)p1;                            \
            hv[jj] = h0; hv[jj + 4] = h1;                                       \
            lv[jj] = (half_t)(p0 - (float)h0);                                  \
            lv[jj + 4] = (half_t)(p1 - (float)h1);                              \
        }                                                                       \
        *(half8*)((char*)Ah + off + sbyte) = hv;                                \
        *(half8*)((char*)Al + off + sbyte) = lv;                                \
    }

#define STEP(IT, XCh, XCl, XNh, XNl, P)                                         \
    {                                                                           \
        const int kxn_ = ((IT) + 1 < 32) ? (IT) + 1 : 31;                       \
        const int kan_ = ((IT) + 2 < 32) ? (IT) + 2 : 31;                       \
        ISSUE_X(XNh, XNl, kxn_);                /* +8 -> 20 in flight */        \
        __builtin_amdgcn_sched_barrier(0);                                      \
        asm volatile("s_waitcnt vmcnt(8)" ::: "memory"); /* drain X(cur),A */   \
        __builtin_amdgcn_sched_barrier(0);                                      \
        CONVERT_WRITE_A((P) ^ 1);               /* buf^1 <- A(IT+1) */          \
        ISSUE_A(kan_);                          /* A(IT+2), +4 in flight */     \
        __builtin_amdgcn_sched_barrier(0);                                      \
        const int pofs_ = (P) * 16384;                                          \
        _Pragma("unroll")                                                       \
        for (int kk = 0; kk < 2; ++kk) {                                        \
            half8 fa_h[2], fa_l[2];                                             \
            _Pragma("unroll")                                                   \
            for (int mt = 0; mt < 2; ++mt) {                                    \
                int r = wm * 32 + mt * 16 + lr;                                 \
                int byte = ((r * 128 + kk * 64 + lg * 16) ^ ((r & 7) << 4))     \
                         + pofs_;                                               \
                fa_h[mt] = *(const half8*)((const char*)Ah + byte);             \
                fa_l[mt] = *(const half8*)((const char*)Al + byte);             \
            }                                                                   \
            __builtin_amdgcn_sched_barrier(0);                                  \
            _Pragma("unroll")                                                   \
            for (int mt = 0; mt < 2; ++mt)                                      \
                _Pragma("unroll")                                               \
                for (int nt = 0; nt < 2; ++nt) {                                \
                    acc[mt][nt] = __builtin_amdgcn_mfma_f32_16x16x32_f16(       \
                        fa_h[mt], XCh[kk][nt], acc[mt][nt], 0, 0, 0);           \
                    acc[mt][nt] = __builtin_amdgcn_mfma_f32_16x16x32_f16(       \
                        fa_l[mt], XCh[kk][nt], acc[mt][nt], 0, 0, 0);           \
                    acc[mt][nt] = __builtin_amdgcn_mfma_f32_16x16x32_f16(       \
                        fa_h[mt], XCl[kk][nt], acc[mt][nt], 0, 0, 0);           \
                }                                                               \
        }                                                                       \
        asm volatile("s_waitcnt lgkmcnt(0)" ::: "memory"); /* publish ds */     \
        __builtin_amdgcn_s_barrier();                                           \
    }

    // ---- prologue: buf0 <- A(0); start X(0), A(1)
    ISSUE_A(0);
    asm volatile("s_waitcnt vmcnt(0)" ::: "memory");
    __builtin_amdgcn_sched_barrier(0);
    CONVERT_WRITE_A(0);
    ISSUE_X(XAh, XAl, 0);
    ISSUE_A(1);
    asm volatile("s_waitcnt lgkmcnt(0)" ::: "memory");
    __builtin_amdgcn_s_barrier();

    // ---- main loop, 2-step unrolled
    for (int it2 = 0; it2 < 32; it2 += 2) {
        STEP(it2,     XAh, XAl, XBh, XBl, 0);
        STEP(it2 + 1, XBh, XBl, XAh, XAl, 1);
    }
    // drain ALL in-flight loads before epilogue register reuse (crash fix)
    asm volatile("s_waitcnt vmcnt(0)" ::: "memory");
    __builtin_amdgcn_sched_barrier(0);

    // C store
#pragma unroll
    for (int mt = 0; mt < 2; ++mt)
#pragma unroll
        for (int nt = 0; nt < 2; ++nt) {
            int jcol = jBase + wn * 32 + nt * 16 + lr;
#pragma unroll
            for (int j4 = 0; j4 < 4; ++j4) {
                int mrow = mBase + wm * 32 + mt * 16 + lg * 4 + j4;
                outp[(size_t)mrow * 512 + jcol] = acc[mt][nt][j4];
            }
        }
#undef ISSUE_A
#undef ISSUE_X
#undef CONVERT_WRITE_A
#undef STEP
}

// ---- K2e: x1[kb][j][kc] = relu(xp0+xp1+b1[j&63]) split hi/lo
__global__ __launch_bounds__(256) void k2e(
    const float* __restrict__ p0, const float* __restrict__ p1,
    const float* __restrict__ b1,
    half_t* __restrict__ xhi, half_t* __restrict__ xlo)
{
    int base = blockIdx.x * 256 + threadIdx.x;
#pragma unroll
    for (int rpt = 0; rpt < 4; ++rpt) {
        int idx4 = base + rpt * 131072;
        int m = idx4 >> 7, jq = idx4 & 127;
        int j0 = jq * 4, d0 = j0 & 63;
        size_t e = (size_t)m * 512 + j0;
        f32x4 v = *(const f32x4*)(p0 + e);
        f32x4 u = *(const f32x4*)(p1 + e);
        f32x4 bb = *(const f32x4*)(b1 + d0);
        size_t obase = ((size_t)(m >> 6) * 512 + j0) * 64 + (m & 63);
#pragma unroll
        for (int jj = 0; jj < 4; ++jj) {
            float x = v[jj] + u[jj] + bb[jj];
            x = fmaxf(x, 0.f);
            half_t hh = (half_t)x;
            xhi[obase + (size_t)jj * 64] = hh;
            xlo[obase + (size_t)jj * 64] = (half_t)(x - (float)hh);
        }
    }
}

// ---- K4: cc = Y@W2 + b2 (fp32, full W2 in LDS, static acc indices) + LSTM pointwise.
__global__ __launch_bounds__(256) void k4_final(
    const float* __restrict__ y0, const float* __restrict__ y1,
    const float* __restrict__ w2, const float* __restrict__ b2,
    const float* __restrict__ ccur,
    float* __restrict__ outh, float* __restrict__ outc)
{
    __shared__ float Yt[64 * 64];
    __shared__ float W2s[64 * 256];
    const int t = threadIdx.x;
    const int cb = t & 15, rb = t >> 4;
    const int rowBase = blockIdx.x * 64;
    const int bIdx = rowBase >> 12, mBase = rowBase & 4095;

#pragma unroll
    for (int i = 0; i < 4; ++i) {
        int id4 = t + i * 256;
        int r = id4 >> 4, dc = id4 & 15;
        size_t g = (size_t)(mBase + r) * 512 + bIdx * 64 + dc * 4;
        f32x4 v = *(const f32x4*)(y0 + g);
        f32x4 u = *(const f32x4*)(y1 + g);
#pragma unroll
        for (int jj = 0; jj < 4; ++jj) Yt[(dc * 4 + jj) * 64 + r] = v[jj] + u[jj];
    }
#pragma unroll
    for (int i = 0; i < 16; ++i) {
        int id4 = t + i * 256;
        *(f32x4*)(W2s + id4 * 4) = *(const f32x4*)(w2 + id4 * 4);
    }
    __syncthreads();

    const f32x4 z = {0.f, 0.f, 0.f, 0.f};
    f32x4 accG[4][4];
#pragma unroll
    for (int g = 0; g < 4; ++g)
#pragma unroll
        for (int r8 = 0; r8 < 4; ++r8) accG[g][r8] = z;

    for (int d = 0; d < 64; ++d) {
        f32x4 y4 = *(const f32x4*)(Yt + d * 64 + rb * 4);
#pragma unroll
        for (int g = 0; g < 4; ++g) {
            f32x4 w4 = *(const f32x4*)(W2s + d * 256 + g * 64 + cb * 4);
#pragma unroll
            for (int r8 = 0; r8 < 4; ++r8) accG[g][r8] += w4 * y4[r8];
        }
    }

    float b2i[4], b2f[4], b2o[4], b2g[4];
#pragma unroll
    for (int jj = 0; jj < 4; ++jj) {
        b2i[jj] = b2[0 * 64 + cb * 4 + jj];
        b2f[jj] = b2[1 * 64 + cb * 4 + jj];
        b2o[jj] = b2[2 * 64 + cb * 4 + jj];
        b2g[jj] = b2[3 * 64 + cb * 4 + jj];
    }
#pragma unroll
    for (int r8 = 0; r8 < 4; ++r8) {
        int row = rowBase + rb * 4 + r8;
        f32x4 c4 = *(const f32x4*)(ccur + (size_t)row * 64 + cb * 4);
        f32x4 hv, cv;
#pragma unroll
        for (int jj = 0; jj < 4; ++jj) {
            float ii = sigmoidf_(accG[0][r8][jj] + b2i[jj]);
            float ff = sigmoidf_(accG[1][r8][jj] + b2f[jj]);
            float oo = sigmoidf_(accG[2][r8][jj] + b2o[jj]);
            float gg = tanhf_(accG[3][r8][jj] + b2g[jj]);
            float cn = ff * c4[jj] + ii * gg;
            float hn = oo * tanhf_(cn);
            hv[jj] = hn;
            cv[jj] = cn;
        }
        *(f32x4*)(outh + (size_t)row * 64 + cb * 4) = hv;
        *(f32x4*)(outc + (size_t)row * 64 + cb * 4) = cv;
    }
}

extern "C" void kernel_launch(void* const* d_in, const int* in_sizes, int n_in,
                              void* d_out, int out_size, void* d_ws, size_t ws_size,
                              hipStream_t stream) {
    const float* inp   = (const float*)d_in[0];
    const float* hcur  = (const float*)d_in[1];
    const float* ccur  = (const float*)d_in[2];
    const float* adj   = (const float*)d_in[3];
    const float* w1    = (const float*)d_in[4];
    const float* mask1 = (const float*)d_in[5];
    const float* b1    = (const float*)d_in[6];
    const float* w2    = (const float*)d_in[7];
    const float* mask2 = (const float*)d_in[8];
    const float* b2    = (const float*)d_in[9];

    char* ws = (char*)d_ws;
    half_t* w1thi = (half_t*)(ws + OFF_W1THI);
    half_t* w1tlo = (half_t*)(ws + OFF_W1TLO);
    half_t* s1hi  = (half_t*)(ws + OFF_S1HI);
    half_t* s1lo  = (half_t*)(ws + OFF_S1LO);
    half_t* x1hi  = (half_t*)(ws + OFF_S1HI);   // alias: s1 dead after layer-1 gemm
    half_t* x1lo  = (half_t*)(ws + OFF_S1LO);
    float*  xp0   = (float*)(ws + OFF_XP0);
    float*  xp1   = (float*)(ws + OFF_XP1);
    float*  y0    = (float*)(ws + OFF_XP0);     // alias: xp dead after k2e
    float*  y1    = (float*)(ws + OFF_XP1);

    float* hout = (float*)d_out;
    float* cout = hout + (size_t)8 * 4096 * 64;

    prep_w1t<<<24, 256, 0, stream>>>(w1, w1thi, w1tlo);
    k1_gemm<<<512, 256, 0, stream>>>(inp, hcur, w1thi, w1tlo, s1hi, s1lo);
    gemm_bn<<<256, 1024, 0, stream>>>(adj, mask1, s1hi, s1lo, xp0, xp1);
    k2e<<<512, 256, 0, stream>>>(xp0, xp1, b1, x1hi, x1lo);
    gemm_bn<<<256, 1024, 0, stream>>>(adj, mask2, x1hi, x1lo, y0, y1);
    k4_final<<<512, 256, 0, stream>>>(y0, y1, w2, b2, ccur, hout, cout);
}

// Round 13
// 159.474 us; speedup vs baseline: 2.1989x; 2.1244x over previous
//
#include <hip/hip_runtime.h>
#include <hip/hip_bf16.h>
#include <hip/hip_fp16.h>
#include <stdint.h>

typedef _Float16 half_t;
typedef _Float16 half8 __attribute__((ext_vector_type(8)));
typedef float f32x4 __attribute__((ext_vector_type(4)));

#define NN 4096
// ws layout (bytes). S1: fp16 hi/lo [64][512][64] hybrid; x1: SINGLE fp16 in
// s1hi's region (s1 dead after layer-1 gemm); y aliases xp (dead after k2e).
#define OFF_W1THI  0u
#define OFF_W1TLO  16384u
#define OFF_S1HI   32768u
#define OFF_S1LO   (32768u + 4194304u)
#define OFF_XP0    (32768u + 2u*4194304u)
#define OFF_XP1    (OFF_XP0 + 8388608u)
// total 25,198,592 bytes (proven footprint)

__device__ __forceinline__ float sigmoidf_(float x) { return 1.f / (1.f + __expf(-x)); }
__device__ __forceinline__ float tanhf_(float x)    { return 1.f - 2.f / (__expf(2.f * x) + 1.f); }

// ---- K0: transpose + hi/lo split W1 [96][64] -> W1t [64][96] fp16 pairs
__global__ void prep_w1t(const float* __restrict__ w1,
                         half_t* __restrict__ whi, half_t* __restrict__ wlo) {
    int i = blockIdx.x * 256 + threadIdx.x;
    if (i >= 96 * 64) return;
    int c = i >> 6, d = i & 63;
    float v = w1[i];
    half_t h = (half_t)v;
    whi[d * 96 + c] = h;
    wlo[d * 96 + c] = (half_t)(v - (float)h);
}

// ---- K1: S1[kb][j][kc] (j=b*64+d) = sum_c combined[b][n][c]*W1[c][d], 3-pass fp16
__global__ __launch_bounds__(256) void k1_gemm(
    const float* __restrict__ inp, const float* __restrict__ hcur,
    const half_t* __restrict__ wthi, const half_t* __restrict__ wtlo,
    half_t* __restrict__ s1hi, half_t* __restrict__ s1lo)
{
    __shared__ half_t Ch[64 * 96], Cl[64 * 96], Wh[64 * 96], Wl[64 * 96];
    const int t = threadIdx.x;
    const int l = t & 63, w = t >> 6, lr = l & 15, lg = l >> 4;
    const int b = blockIdx.x >> 6;
    const int kb = blockIdx.x & 63;
    const int nBase = kb * 64;

    {
        const uint32_t* sh = (const uint32_t*)wthi;
        const uint32_t* sl = (const uint32_t*)wtlo;
        uint32_t* dh = (uint32_t*)Wh;
        uint32_t* dl = (uint32_t*)Wl;
        for (int i = t; i < 3072; i += 256) { dh[i] = sh[i]; dl[i] = sl[i]; }
    }
#pragma unroll
    for (int i = 0; i < 6; ++i) {
        int f4 = t + i * 256;
        int row = f4 / 24, slot = f4 % 24;
        int n = nBase + row;
        f32x4 v; int c0;
        if (slot < 8) { c0 = slot * 4; v = *(const f32x4*)(inp + ((size_t)b * NN + n) * 32 + c0); }
        else { c0 = 32 + (slot - 8) * 4; v = *(const f32x4*)(hcur + ((size_t)b * NN + n) * 64 + (c0 - 32)); }
#pragma unroll
        for (int jj = 0; jj < 4; ++jj) {
            float x = v[jj];
            half_t hh = (half_t)x;
            Ch[row * 96 + c0 + jj] = hh;
            Cl[row * 96 + c0 + jj] = (half_t)(x - (float)hh);
        }
    }
    __syncthreads();

    const f32x4 z = {0.f, 0.f, 0.f, 0.f};
    f32x4 acc[4] = {z, z, z, z};
#pragma unroll
    for (int kk = 0; kk < 3; ++kk) {
        const int qo = (w * 16 + lr) * 96 + kk * 32 + lg * 8;
        half8 cf_h = *(const half8*)(Ch + qo);
        half8 cf_l = *(const half8*)(Cl + qo);
#pragma unroll
        for (int dt = 0; dt < 4; ++dt) {
            const int po = (dt * 16 + lr) * 96 + kk * 32 + lg * 8;
            half8 wf_h = *(const half8*)(Wh + po);
            half8 wf_l = *(const half8*)(Wl + po);
            acc[dt] = __builtin_amdgcn_mfma_f32_16x16x32_f16(wf_h, cf_h, acc[dt], 0, 0, 0);
            acc[dt] = __builtin_amdgcn_mfma_f32_16x16x32_f16(wf_h, cf_l, acc[dt], 0, 0, 0);
            acc[dt] = __builtin_amdgcn_mfma_f32_16x16x32_f16(wf_l, cf_h, acc[dt], 0, 0, 0);
        }
    }
    const int kc = w * 16 + lr;
#pragma unroll
    for (int dt = 0; dt < 4; ++dt)
#pragma unroll
        for (int j4 = 0; j4 < 4; ++j4) {
            int d = dt * 16 + lg * 4 + j4;
            float v = acc[dt][j4];
            half_t hh = (half_t)v;
            size_t o = ((size_t)kb * 512 + b * 64 + d) * 64 + kc;
            s1hi[o] = hh;
            s1lo[o] = (half_t)(v - (float)hh);
        }
}

// ---- K2/K3 unified: C[m][j] = sum_n (adj*mask)[m,n] * X[n][j]
// M=4096, N(j)=512, K=4096; BM=BN=128, BK=64, ks x2 partials.
// 1024 threads = 16 waves (4m x 4n), wave tile 32x32.
// Double-buffered LDS + reg-staged prefetch + sched_barrier fences (round-9
// best-known-good skeleton).
// PASSES=3 (layer 1): A hi/lo + X hi/lo, 3 MFMA per fragment pair — needed
//   because S1-storage & A1-rounding errors are amplified by the two-hop
//   operator A2·A1 (||G||_rms ~ 65536).
// PASSES=1 (layer 2): A single fp16 + X single fp16, 1 MFMA — x1-storage and
//   A2-rounding errors see only one hop (sqrt(sum A2^2) ~ 37): ~0.003 abs.
template<int PASSES>
__global__ __launch_bounds__(1024) void gemm_bn(
    const float* __restrict__ adj, const float* __restrict__ mask,
    const half_t* __restrict__ xhi, const half_t* __restrict__ xlo,
    float* __restrict__ out0, float* __restrict__ out1)
{
    __shared__ half_t Ah[2 * 128 * 64];
    __shared__ half_t Xh[2 * 128 * 64];
    __shared__ half_t Al[PASSES == 3 ? 2 * 128 * 64 : 4];
    __shared__ half_t Xl[PASSES == 3 ? 2 * 128 * 64 : 4];
    const int t = threadIdx.x;
    const int l = t & 63, w = t >> 6, lr = l & 15, lg = l >> 4;
    const int wm = w >> 2, wn = w & 3;
    const int bx = blockIdx.x;
    const int mt_ = bx & 31, ks = (bx >> 5) & 1, nb = bx >> 6;
    const int mBase = mt_ * 128, jBase = nb * 128;
    float* __restrict__ outp = ks ? out1 : out0;

    const f32x4 z = {0.f, 0.f, 0.f, 0.f};
    f32x4 acc[2][2] = {{z, z}, {z, z}};

    const int srow = t >> 3, skc = t & 7;   // staging slot: 128 rows x 8 chunks
    const int sbyte = (srow * 128 + skc * 16) ^ ((srow & 7) << 4);

    // prefetch registers (tile it+1)
    f32x4 pa0, pa1, pm0, pm1;
    half8 pxh, pxl;

#define ISSUE_LOADS(IT)                                                          \
    {                                                                            \
        const int kb = ks * 32 + (IT);                                           \
        const int k0 = kb * 64;                                                  \
        size_t ga = (size_t)(mBase + srow) * NN + k0 + skc * 8;                  \
        pa0 = *(const f32x4*)(adj + ga);                                         \
        pa1 = *(const f32x4*)(adj + ga + 4);                                     \
        pm0 = *(const f32x4*)(mask + ga);                                        \
        pm1 = *(const f32x4*)(mask + ga + 4);                                    \
        size_t gx = ((size_t)kb * 512 + jBase + srow) * 64 + skc * 8;            \
        pxh = *(const half8*)(xhi + gx);                                         \
        if constexpr (PASSES == 3) pxl = *(const half8*)(xlo + gx);              \
    }

#define CONVERT_WRITE(P)                                                         \
    {                                                                            \
        const int off = (P) * 16384;                                             \
        half8 hv, lv;                                                            \
        _Pragma("unroll")                                                        \
        for (int jj = 0; jj < 4; ++jj) {                                         \
            float p0 = pa0[jj] * pm0[jj];                                        \
            float p1 = pa1[jj] * pm1[jj];                                        \
            half_t h0 = (half_t)p0, h1 = (half_t)p1;                             \
            hv[jj] = h0; hv[jj + 4] = h1;                                        \
            if constexpr (PASSES == 3) {                                         \
                lv[jj] = (half_t)(p0 - (float)h0);                               \
                lv[jj + 4] = (half_t)(p1 - (float)h1);                           \
            }                                                                    \
        }                                                                        \
        *(half8*)((char*)Ah + off + sbyte) = hv;                                 \
        *(half8*)((char*)Xh + off + sbyte) = pxh;                                \
        if constexpr (PASSES == 3) {                                             \
            *(half8*)((char*)Al + off + sbyte) = lv;                             \
            *(half8*)((char*)Xl + off + sbyte) = pxl;                            \
        }                                                                        \
    }

    ISSUE_LOADS(0);
    CONVERT_WRITE(0);
    __syncthreads();

    for (int it = 0; it < 32; ++it) {
        const int p = it & 1;
        const int pofs = p * 16384;
        if (it + 1 < 32) ISSUE_LOADS(it + 1);      // global loads in flight
        __builtin_amdgcn_sched_barrier(0);          // ...and they STAY issued here
#pragma unroll
        for (int kk = 0; kk < 2; ++kk) {
            half8 fa_h[2], fa_l[2], fx_h[2], fx_l[2];
#pragma unroll
            for (int mt = 0; mt < 2; ++mt) {
                int r = wm * 32 + mt * 16 + lr;
                int byte = ((r * 128 + kk * 64 + lg * 16) ^ ((r & 7) << 4)) + pofs;
                fa_h[mt] = *(const half8*)((const char*)Ah + byte);
                if constexpr (PASSES == 3)
                    fa_l[mt] = *(const half8*)((const char*)Al + byte);
            }
#pragma unroll
            for (int nt = 0; nt < 2; ++nt) {
                int r = wn * 32 + nt * 16 + lr;
                int byte = ((r * 128 + kk * 64 + lg * 16) ^ ((r & 7) << 4)) + pofs;
                fx_h[nt] = *(const half8*)((const char*)Xh + byte);
                if constexpr (PASSES == 3)
                    fx_l[nt] = *(const half8*)((const char*)Xl + byte);
            }
            __builtin_amdgcn_sched_barrier(0);      // batch all reads, one drain
#pragma unroll
            for (int mt = 0; mt < 2; ++mt)
#pragma unroll
                for (int nt = 0; nt < 2; ++nt) {
                    acc[mt][nt] = __builtin_amdgcn_mfma_f32_16x16x32_f16(fa_h[mt], fx_h[nt], acc[mt][nt], 0, 0, 0);
                    if constexpr (PASSES == 3) {
                        acc[mt][nt] = __builtin_amdgcn_mfma_f32_16x16x32_f16(fa_l[mt], fx_h[nt], acc[mt][nt], 0, 0, 0);
                        acc[mt][nt] = __builtin_amdgcn_mfma_f32_16x16x32_f16(fa_h[mt], fx_l[nt], acc[mt][nt], 0, 0, 0);
                    }
                }
        }
        if (it + 1 < 32) CONVERT_WRITE(p ^ 1);     // write NEXT buffer (safe: other
                                                   // waves read buf p this step)
        __syncthreads();                           // one barrier per k-step
    }

    // C store: row m' = mBase+wm*32+mt*16+lg*4+j4, col j' = jBase+wn*32+nt*16+lr
#pragma unroll
    for (int mt = 0; mt < 2; ++mt)
#pragma unroll
        for (int nt = 0; nt < 2; ++nt) {
            int jcol = jBase + wn * 32 + nt * 16 + lr;
#pragma unroll
            for (int j4 = 0; j4 < 4; ++j4) {
                int mrow = mBase + wm * 32 + mt * 16 + lg * 4 + j4;
                outp[(size_t)mrow * 512 + jcol] = acc[mt][nt][j4];
            }
        }
#undef ISSUE_LOADS
#undef CONVERT_WRITE
}

// ---- K2e: x1[kb][j][kc] = relu(xp0+xp1+b1[j&63]) — SINGLE fp16 (one-hop error)
__global__ __launch_bounds__(256) void k2e(
    const float* __restrict__ p0, const float* __restrict__ p1,
    const float* __restrict__ b1,
    half_t* __restrict__ x1s)
{
    int base = blockIdx.x * 256 + threadIdx.x;
#pragma unroll
    for (int rpt = 0; rpt < 4; ++rpt) {
        int idx4 = base + rpt * 131072;
        int m = idx4 >> 7, jq = idx4 & 127;
        int j0 = jq * 4, d0 = j0 & 63;
        size_t e = (size_t)m * 512 + j0;
        f32x4 v = *(const f32x4*)(p0 + e);
        f32x4 u = *(const f32x4*)(p1 + e);
        f32x4 bb = *(const f32x4*)(b1 + d0);
        size_t obase = ((size_t)(m >> 6) * 512 + j0) * 64 + (m & 63);
#pragma unroll
        for (int jj = 0; jj < 4; ++jj) {
            float x = v[jj] + u[jj] + bb[jj];
            x = fmaxf(x, 0.f);
            x1s[obase + (size_t)jj * 64] = (half_t)x;
        }
    }
}

// ---- K4: cc = Y@W2 + b2 (fp32, full W2 in LDS, static acc indices) + LSTM pointwise.
__global__ __launch_bounds__(256) void k4_final(
    const float* __restrict__ y0, const float* __restrict__ y1,
    const float* __restrict__ w2, const float* __restrict__ b2,
    const float* __restrict__ ccur,
    float* __restrict__ outh, float* __restrict__ outc)
{
    __shared__ float Yt[64 * 64];
    __shared__ float W2s[64 * 256];
    const int t = threadIdx.x;
    const int cb = t & 15, rb = t >> 4;
    const int rowBase = blockIdx.x * 64;
    const int bIdx = rowBase >> 12, mBase = rowBase & 4095;

#pragma unroll
    for (int i = 0; i < 4; ++i) {
        int id4 = t + i * 256;
        int r = id4 >> 4, dc = id4 & 15;
        size_t g = (size_t)(mBase + r) * 512 + bIdx * 64 + dc * 4;
        f32x4 v = *(const f32x4*)(y0 + g);
        f32x4 u = *(const f32x4*)(y1 + g);
#pragma unroll
        for (int jj = 0; jj < 4; ++jj) Yt[(dc * 4 + jj) * 64 + r] = v[jj] + u[jj];
    }
#pragma unroll
    for (int i = 0; i < 16; ++i) {
        int id4 = t + i * 256;
        *(f32x4*)(W2s + id4 * 4) = *(const f32x4*)(w2 + id4 * 4);
    }
    __syncthreads();

    const f32x4 z = {0.f, 0.f, 0.f, 0.f};
    f32x4 accG[4][4];
#pragma unroll
    for (int g = 0; g < 4; ++g)
#pragma unroll
        for (int r8 = 0; r8 < 4; ++r8) accG[g][r8] = z;

    for (int d = 0; d < 64; ++d) {
        f32x4 y4 = *(const f32x4*)(Yt + d * 64 + rb * 4);
#pragma unroll
        for (int g = 0; g < 4; ++g) {
            f32x4 w4 = *(const f32x4*)(W2s + d * 256 + g * 64 + cb * 4);
#pragma unroll
            for (int r8 = 0; r8 < 4; ++r8) accG[g][r8] += w4 * y4[r8];
        }
    }

    float b2i[4], b2f[4], b2o[4], b2g[4];
#pragma unroll
    for (int jj = 0; jj < 4; ++jj) {
        b2i[jj] = b2[0 * 64 + cb * 4 + jj];
        b2f[jj] = b2[1 * 64 + cb * 4 + jj];
        b2o[jj] = b2[2 * 64 + cb * 4 + jj];
        b2g[jj] = b2[3 * 64 + cb * 4 + jj];
    }
#pragma unroll
    for (int r8 = 0; r8 < 4; ++r8) {
        int row = rowBase + rb * 4 + r8;
        f32x4 c4 = *(const f32x4*)(ccur + (size_t)row * 64 + cb * 4);
        f32x4 hv, cv;
#pragma unroll
        for (int jj = 0; jj < 4; ++jj) {
            float ii = sigmoidf_(accG[0][r8][jj] + b2i[jj]);
            float ff = sigmoidf_(accG[1][r8][jj] + b2f[jj]);
            float oo = sigmoidf_(accG[2][r8][jj] + b2o[jj]);
            float gg = tanhf_(accG[3][r8][jj] + b2g[jj]);
            float cn = ff * c4[jj] + ii * gg;
            float hn = oo * tanhf_(cn);
            hv[jj] = hn;
            cv[jj] = cn;
        }
        *(f32x4*)(outh + (size_t)row * 64 + cb * 4) = hv;
        *(f32x4*)(outc + (size_t)row * 64 + cb * 4) = cv;
    }
}

extern "C" void kernel_launch(void* const* d_in, const int* in_sizes, int n_in,
                              void* d_out, int out_size, void* d_ws, size_t ws_size,
                              hipStream_t stream) {
    const float* inp   = (const float*)d_in[0];
    const float* hcur  = (const float*)d_in[1];
    const float* ccur  = (const float*)d_in[2];
    const float* adj   = (const float*)d_in[3];
    const float* w1    = (const float*)d_in[4];
    const float* mask1 = (const float*)d_in[5];
    const float* b1    = (const float*)d_in[6];
    const float* w2    = (const float*)d_in[7];
    const float* mask2 = (const float*)d_in[8];
    const float* b2    = (const float*)d_in[9];

    char* ws = (char*)d_ws;
    half_t* w1thi = (half_t*)(ws + OFF_W1THI);
    half_t* w1tlo = (half_t*)(ws + OFF_W1TLO);
    half_t* s1hi  = (half_t*)(ws + OFF_S1HI);
    half_t* s1lo  = (half_t*)(ws + OFF_S1LO);
    half_t* x1s   = (half_t*)(ws + OFF_S1HI);   // alias: s1 dead after layer-1 gemm
    float*  xp0   = (float*)(ws + OFF_XP0);
    float*  xp1   = (float*)(ws + OFF_XP1);
    float*  y0    = (float*)(ws + OFF_XP0);     // alias: xp dead after k2e
    float*  y1    = (float*)(ws + OFF_XP1);

    float* hout = (float*)d_out;
    float* cout = hout + (size_t)8 * 4096 * 64;

    prep_w1t<<<24, 256, 0, stream>>>(w1, w1thi, w1tlo);
    k1_gemm<<<512, 256, 0, stream>>>(inp, hcur, w1thi, w1tlo, s1hi, s1lo);
    gemm_bn<3><<<256, 1024, 0, stream>>>(adj, mask1, s1hi, s1lo, xp0, xp1);
    k2e<<<512, 256, 0, stream>>>(xp0, xp1, b1, x1s);
    gemm_bn<1><<<256, 1024, 0, stream>>>(adj, mask2, x1s, x1s, y0, y1);
    k4_final<<<512, 256, 0, stream>>>(y0, y1, w2, b2, ccur, hout, cout);
}